// Round 1
// baseline (102.752 us; speedup 1.0000x reference)
//
#include <hip/hip_runtime.h>

// QuantGelu: y = pre_x_int * sigmoid_int * (scaler/128)
// pre_x_int = clip(round(x/scaler), -128, 127)
// sigmoid via integer shift-exp softmax over {x_int, -row_max}
//
// Shapes: x[4,2048,4096] f32, scaler[4096] f32 -> y same as x.
// One block per row (8192 rows), 256 threads, 16 elems/thread.

#define D 4096
#define BLK 256
#define EPT 16  // elements per thread

__device__ __forceinline__ float int_exp_shift(float xi, float x0) {
    // xi integer-valued, x0 = floor(-1/sf) < 0
    xi = xi + floorf(xi * 0.5f) - floorf(xi * 0.0625f);
    xi = fmaxf(xi, 15.0f * x0);
    float q = floorf(xi / x0);          // IEEE div, matches np
    float r = xi - x0 * q;              // exact (small integers)
    float e = r * 0.5f - x0;            // multiple of 0.5, exact
    return fmaxf(floorf(e * exp2f(15.0f - q)), 0.0f);
}

__global__ __launch_bounds__(BLK) void quantgelu_kernel(
    const float* __restrict__ x, const float* __restrict__ scaler,
    float* __restrict__ out)
{
    const int row = blockIdx.x;
    const int tid = threadIdx.x;
    const long long base = (long long)row * D;

    float pre[EPT];
    float scl[EPT];

    float vmax = -INFINITY;
    #pragma unroll
    for (int k = 0; k < 4; ++k) {
        const int col = k * (BLK * 4) + tid * 4;
        const float4 xv = *reinterpret_cast<const float4*>(x + base + col);
        const float4 sv = *reinterpret_cast<const float4*>(scaler + col);
        const float xs[4] = {xv.x, xv.y, xv.z, xv.w};
        const float ss[4] = {sv.x, sv.y, sv.z, sv.w};
        #pragma unroll
        for (int j = 0; j < 4; ++j) {
            float p = rintf(xs[j] / ss[j]);            // round half-even
            p = fminf(fmaxf(p, -128.0f), 127.0f);
            pre[k * 4 + j] = p;
            scl[k * 4 + j] = ss[j];
            vmax = fmaxf(vmax, p);
        }
    }

    // wave (64-lane) butterfly max
    #pragma unroll
    for (int off = 1; off < 64; off <<= 1)
        vmax = fmaxf(vmax, __shfl_xor(vmax, off));
    __shared__ float smax[BLK / 64];
    if ((tid & 63) == 0) smax[tid >> 6] = vmax;
    __syncthreads();
    vmax = fmaxf(fmaxf(smax[0], smax[1]), fmaxf(smax[2], smax[3]));

    const float xm = -vmax;
    const float I32M = 2147483647.0f;   // rounds to 2147483648.0f, same as np.float32

    #pragma unroll
    for (int k = 0; k < 4; ++k) {
        float4 ov;
        float* o = reinterpret_cast<float*>(&ov);
        #pragma unroll
        for (int j = 0; j < 4; ++j) {
            const int i = k * 4 + j;
            const float s  = scl[i];
            const float sf = s * 1.702f;
            const float x0 = floorf(-1.0f / sf);       // IEEE div

            const float ei = int_exp_shift(pre[i] - vmax, x0);
            const float em = int_exp_shift(xm, x0);

            const float esum   = fminf(ei + em, I32M);
            const float factor = floorf(I32M / esum);  // IEEE div
            const float sig    = floorf((ei * factor) * (1.0f / 16777216.0f)); // /2^24 exact scale
            o[j] = (pre[i] * sig) * (s * 0.0078125f);  // * scaler/128
        }
        *reinterpret_cast<float4*>(out + base + k * (BLK * 4) + tid * 4) = ov;
    }
}

extern "C" void kernel_launch(void* const* d_in, const int* in_sizes, int n_in,
                              void* d_out, int out_size, void* d_ws, size_t ws_size,
                              hipStream_t stream) {
    const float* x      = (const float*)d_in[0];
    const float* scaler = (const float*)d_in[1];
    float* out          = (float*)d_out;

    const int nrows = in_sizes[0] / D;   // 4*2048 = 8192
    quantgelu_kernel<<<nrows, BLK, 0, stream>>>(x, scaler, out);
}

// Round 2
// 72.971 us; speedup vs baseline: 1.4081x; 1.4081x over previous
//
#include <hip/hip_runtime.h>

// QuantGelu: y = pre_x_int * sigmoid_int * (scaler/128)
// pre_x_int = clip(round(x/scaler), -128, 127)
// sigmoid via integer shift-exp softmax over {x_int, -row_max}
//
// Shapes: x[4,2048,4096] f32, scaler[4096] f32 -> y same shape.
// 256 threads/block, 16 channels/thread, 8 rows/block (channel constants
// hoisted across rows). Row max via wave butterfly + 4-slot LDS.

#define D 4096
#define BLK 256
#define CPT 16          // channels per thread
#define RPB 8           // rows per block

// core of _int_exp_shift after the 1.4375 transform + clamp:
// q = floor(xi/x0) computed as floor(xi*rx0) + exact integer correction.
// All values are integer-valued floats < 2^24 -> fma remainders exact.
__device__ __forceinline__ float exp_core(float xi, float x0, float rx0) {
    float q  = floorf(xi * rx0);
    float rh = fmaf(-x0, q, xi);            // xi - x0*q, exact
    // valid remainder range is (x0, 0]
    float adj = (rh > 0.0f) ? -1.0f : ((rh <= x0) ? 1.0f : 0.0f);
    q += adj;
    rh = fmaf(-x0, adj, rh);                // exact
    float e = fmaf(rh, 0.5f, -x0);          // r/2 - x0 (r/2 exact)
    int qi = (int)q;                        // q in [0,15]
    float pw = __int_as_float((142 - qi) << 23);   // 2^(15-q), exact
    return floorf(e * pw);                  // e > 0 always -> max(.,0) redundant
}

__global__ __launch_bounds__(BLK) void quantgelu_kernel(
    const float* __restrict__ x, const float* __restrict__ scaler,
    float* __restrict__ out, int nrows)
{
    const int tid  = threadIdx.x;
    const int row0 = blockIdx.x * RPB;

    // per-channel constants (hoisted across RPB rows)
    float s_[CPT], x0_[CPT], rx0_[CPT];
    #pragma unroll
    for (int k = 0; k < 4; ++k) {
        const int col = k * (BLK * 4) + tid * 4;
        const float4 sv = *reinterpret_cast<const float4*>(scaler + col);
        const float ss[4] = {sv.x, sv.y, sv.z, sv.w};
        #pragma unroll
        for (int j = 0; j < 4; ++j) {
            const int i = k * 4 + j;
            const float s = ss[j];
            s_[i]   = s;
            const float x0 = floorf(-1.0f / (s * 1.702f));  // IEEE div, 1x per 8 rows
            x0_[i]  = x0;
            rx0_[i] = 1.0f / x0;                            // IEEE div, 1x per 8 rows
        }
    }

    __shared__ float smax[2][BLK / 64];

    // prefetch first row
    long long base = (long long)row0 * D;
    float4 xv[4];
    if (row0 < nrows) {
        #pragma unroll
        for (int k = 0; k < 4; ++k)
            xv[k] = *reinterpret_cast<const float4*>(x + base + k * (BLK * 4) + tid * 4);
    }

    for (int r = 0; r < RPB; ++r) {
        const int row = row0 + r;
        if (row >= nrows) break;            // block-uniform

        // prefetch next row early (hide HBM latency under the heavy VALU body)
        float4 xn[4];
        if (r + 1 < RPB && row + 1 < nrows) {
            #pragma unroll
            for (int k = 0; k < 4; ++k)
                xn[k] = *reinterpret_cast<const float4*>(x + base + D + k * (BLK * 4) + tid * 4);
        }

        // phase 1: quantize + row max
        float pre[CPT];
        float vmax = -INFINITY;
        const float* xf = reinterpret_cast<const float*>(xv);
        #pragma unroll
        for (int i = 0; i < CPT; ++i) {
            float p = rintf(xf[i] / s_[i]);              // IEEE div (exactness-critical)
            p = fminf(fmaxf(p, -128.0f), 127.0f);
            pre[i] = p;
            vmax = fmaxf(vmax, p);
        }

        // 64-lane butterfly max, then cross-wave via LDS (double-buffered: 1 sync/row)
        #pragma unroll
        for (int off = 1; off < 64; off <<= 1)
            vmax = fmaxf(vmax, __shfl_xor(vmax, off));
        const int buf = r & 1;
        if ((tid & 63) == 0) smax[buf][tid >> 6] = vmax;
        __syncthreads();
        vmax = fmaxf(fmaxf(smax[buf][0], smax[buf][1]),
                     fmaxf(smax[buf][2], smax[buf][3]));

        // phase 2: shift-exp softmax + output
        const float xm = -vmax;
        const float xmt = xm + floorf(xm * 0.5f) - floorf(xm * 0.0625f);  // per-row hoist

        float res[CPT];
        #pragma unroll
        for (int i = 0; i < CPT; ++i) {
            const float x0  = x0_[i];
            const float rx0 = rx0_[i];
            const float c15 = 15.0f * x0;

            float xi = pre[i] - vmax;
            xi = xi + floorf(xi * 0.5f) - floorf(xi * 0.0625f);
            xi = fmaxf(xi, c15);
            const float ei = exp_core(xi, x0, rx0);

            const float em = exp_core(fmaxf(xmt, c15), x0, rx0);

            const float esum   = fminf(ei + em, 2147483648.0f);
            const float factor = floorf(2147483648.0f / esum);   // IEEE div (exactness-critical)
            const float sig    = floorf((ei * factor) * (1.0f / 16777216.0f)); // /2^24 exact
            res[i] = (pre[i] * sig) * (s_[i] * 0.0078125f);
        }

        #pragma unroll
        for (int k = 0; k < 4; ++k) {
            float4 ov;
            ov.x = res[k * 4 + 0]; ov.y = res[k * 4 + 1];
            ov.z = res[k * 4 + 2]; ov.w = res[k * 4 + 3];
            *reinterpret_cast<float4*>(out + base + k * (BLK * 4) + tid * 4) = ov;
        }

        base += D;
        #pragma unroll
        for (int k = 0; k < 4; ++k) xv[k] = xn[k];
    }
}

extern "C" void kernel_launch(void* const* d_in, const int* in_sizes, int n_in,
                              void* d_out, int out_size, void* d_ws, size_t ws_size,
                              hipStream_t stream) {
    const float* x      = (const float*)d_in[0];
    const float* scaler = (const float*)d_in[1];
    float* out          = (float*)d_out;

    const int nrows = in_sizes[0] / D;                 // 8192
    const int grid  = (nrows + RPB - 1) / RPB;         // 1024
    quantgelu_kernel<<<grid, BLK, 0, stream>>>(x, scaler, out, nrows);
}

// Round 3
// 66.122 us; speedup vs baseline: 1.5540x; 1.1036x over previous
//
#include <hip/hip_runtime.h>

// QuantGelu: y = pre_x_int * sigmoid_int * (scaler/128)
//   pre_x_int = clip(round(x/scaler), -128, 127)  [per-channel scaler, D=4096]
//   sigmoid via integer shift-exp over {x_int, -row_max}
//
// Round-3 structure: BLK=512 threads, CPT=8 channels/thread, RPB=8 rows/block.
// em = int_exp_shift(-row_max) depends only on (row, x0) and x0 is a small
// negative integer -> per-row 64-entry LDS table, one ds_read per element.
// floor(xi/x0) via eps-biased reciprocal (exact for |x0|<=64, see proof).

#define D 4096
#define BLK 512
#define CPT 8           // BLK*CPT == D
#define RPB 8
#define NW (BLK / 64)   // 8 waves
#define TSZ 64          // em table covers x0 in [-64, -1]
#define EPS 1e-4f

// Exact floor(fl(xi/x0)) for integer-valued xi, x0 with |x0| <= 64, ratio in [0,15]:
//  - if x0 | xi: t = (n(1+d1) + EPS)(1+d2), |n*d1| <= 15*6e-8 ~ 9e-7 < EPS -> floor = n
//  - else: |ratio - n| >= 1/64 = 0.0156 >> EPS + 1e-6 -> floor unchanged;
//    reference's fl(xi/x0) also cannot cross an integer (halfulp ~ 9e-7 << 1/64).
__device__ __forceinline__ float exp_fast(float xi, float nx0, float rx0) {
    // xi already transformed and clamped to [15*x0, 0]
    const float q  = floorf(fmaf(xi, rx0, EPS));
    const float r  = fmaf(nx0, q, xi);           // xi - x0*q, exact (small ints)
    const float e  = fmaf(r, 0.5f, nx0);         // r/2 - x0, exact
    const int   qi = (int)q;                      // q in [0,15]
    const float pw = __int_as_float((142 - qi) << 23);  // 2^(15-q), exact
    return floorf(e * pw);                        // e > 0 -> max(.,0) redundant
}

// Fully-IEEE path, exact for any x0 (slow; only for blocks seeing |x0| > 64).
__device__ __forceinline__ float exp_slow(float xi, float x0) {
    xi = fmaxf(xi, 15.0f * x0);
    const float q = floorf(xi / x0);              // IEEE div
    const float r = fmaf(-x0, q, xi);
    const float e = fmaf(r, 0.5f, -x0);
    return fmaxf(floorf(e * ldexpf(1.0f, 15 - (int)q)), 0.0f);
}

__global__ __launch_bounds__(BLK) void quantgelu_kernel(
    const float* __restrict__ x, const float* __restrict__ scaler,
    float* __restrict__ out, int nrows)
{
    const int tid = threadIdx.x;
    const int wid = tid >> 6;
    const int row0 = blockIdx.x * RPB;

    // per-channel constants, hoisted across RPB rows
    float s_[CPT], nx0_[CPT], rx0_[CPT], s128_[CPT];
    int   bo_[CPT];
    bool  ok = true;
    #pragma unroll
    for (int k = 0; k < CPT / 4; ++k) {
        const int col = k * (BLK * 4) + tid * 4;
        const float4 sv = *reinterpret_cast<const float4*>(scaler + col);
        const float ss[4] = {sv.x, sv.y, sv.z, sv.w};
        #pragma unroll
        for (int j = 0; j < 4; ++j) {
            const int i = k * 4 + j;
            const float s  = ss[j];
            const float x0 = floorf(-1.0f / (s * 1.702f));  // IEEE div, 1x per 8 rows
            s_[i]    = s;
            nx0_[i]  = -x0;
            rx0_[i]  = 1.0f / x0;                           // IEEE div, 1x per 8 rows
            s128_[i] = s * 0.0078125f;
            ok &= (x0 >= -64.0f);                           // x0 <= -1 always (s > 0)
            bo_[i] = min(max((int)x0 + TSZ, 0), TSZ - 1);   // table index, clamped
        }
    }
    const bool allok = __all(ok);   // wave-uniform path select

    // em-table lane constants (wave 0 only), computed once per block
    float nx0t = 0.f, rx0t = 0.f, c15t = 0.f;
    if (tid < TSZ) {
        const float x0t = (float)(tid - TSZ);   // -64 .. -1
        nx0t = -x0t;
        rx0t = 1.0f / x0t;                      // IEEE div, once per block
        c15t = 15.0f * x0t;
    }

    __shared__ __align__(16) float smax[NW];
    __shared__ float emt[TSZ];

    long long base = (long long)row0 * D;
    float4 xv[CPT / 4];
    if (row0 < nrows) {
        #pragma unroll
        for (int k = 0; k < CPT / 4; ++k)
            xv[k] = *reinterpret_cast<const float4*>(x + base + k * (BLK * 4) + tid * 4);
    }

    for (int r = 0; r < RPB; ++r) {
        const int row = row0 + r;
        if (row >= nrows) break;                // block-uniform

        // prefetch next row under this row's VALU body
        float4 xn[CPT / 4];
        if (r + 1 < RPB && row + 1 < nrows) {
            #pragma unroll
            for (int k = 0; k < CPT / 4; ++k)
                xn[k] = *reinterpret_cast<const float4*>(x + base + D + k * (BLK * 4) + tid * 4);
        }

        // phase 1: quantize + row max
        float pre[CPT];
        float vmax = -INFINITY;
        const float* xf = reinterpret_cast<const float*>(xv);
        #pragma unroll
        for (int i = 0; i < CPT; ++i) {
            float p = rintf(xf[i] / s_[i]);     // IEEE div (exactness-critical)
            p = fminf(fmaxf(p, -128.0f), 127.0f);
            pre[i] = p;
            vmax = fmaxf(vmax, p);
        }
        #pragma unroll
        for (int off = 1; off < 64; off <<= 1)
            vmax = fmaxf(vmax, __shfl_xor(vmax, off));
        if ((tid & 63) == 0) smax[wid] = vmax;
        __syncthreads();
        {
            const float4 a = *reinterpret_cast<const float4*>(smax);
            const float4 b = *reinterpret_cast<const float4*>(smax + 4);
            vmax = fmaxf(fmaxf(fmaxf(a.x, a.y), fmaxf(a.z, a.w)),
                         fmaxf(fmaxf(b.x, b.y), fmaxf(b.z, b.w)));
        }

        // per-row em table: em depends only on (vmax, x0)
        const float xm  = -vmax;
        const float xmt = xm + floorf(xm * 0.5f) - floorf(xm * 0.0625f);
        if (tid < TSZ)
            emt[tid] = exp_fast(fmaxf(xmt, c15t), nx0t, rx0t);
        __syncthreads();

        // phase 2: shift-exp softmax + output
        float res[CPT];
        if (allok) {
            #pragma unroll
            for (int i = 0; i < CPT; ++i) {
                const float nx0 = nx0_[i];
                float xi = pre[i] - vmax;
                xi = xi + floorf(xi * 0.5f) - floorf(xi * 0.0625f);
                xi = fmaxf(xi, -15.0f * nx0);
                const float ei = exp_fast(xi, nx0, rx0_[i]);
                const float em = emt[bo_[i]];               // LDS, off-VALU
                const float esum   = fminf(ei + em, 2147483648.0f);
                const float factor = floorf(2147483648.0f / esum);  // IEEE div
                const float sig    = floorf((ei * factor) * (1.0f / 16777216.0f));
                res[i] = (pre[i] * sig) * s128_[i];
            }
        } else {
            // rare block-uniform exact fallback (|x0| > 64 channels present)
            #pragma unroll
            for (int i = 0; i < CPT; ++i) {
                const float x0 = -nx0_[i];
                float xi = pre[i] - vmax;
                xi = xi + floorf(xi * 0.5f) - floorf(xi * 0.0625f);
                const float ei = exp_slow(xi, x0);
                const float em = exp_slow(xmt, x0);
                const float esum   = fminf(ei + em, 2147483648.0f);
                const float factor = floorf(2147483648.0f / esum);
                const float sig    = floorf((ei * factor) * (1.0f / 16777216.0f));
                res[i] = (pre[i] * sig) * s128_[i];
            }
        }

        #pragma unroll
        for (int k = 0; k < CPT / 4; ++k) {
            float4 ov;
            ov.x = res[k * 4 + 0]; ov.y = res[k * 4 + 1];
            ov.z = res[k * 4 + 2]; ov.w = res[k * 4 + 3];
            *reinterpret_cast<float4*>(out + base + k * (BLK * 4) + tid * 4) = ov;
        }

        base += D;
        #pragma unroll
        for (int k = 0; k < CPT / 4; ++k) xv[k] = xn[k];
    }
}

extern "C" void kernel_launch(void* const* d_in, const int* in_sizes, int n_in,
                              void* d_out, int out_size, void* d_ws, size_t ws_size,
                              hipStream_t stream) {
    const float* x      = (const float*)d_in[0];
    const float* scaler = (const float*)d_in[1];
    float* out          = (float*)d_out;

    const int nrows = in_sizes[0] / D;                 // 8192
    const int grid  = (nrows + RPB - 1) / RPB;         // 1024
    quantgelu_kernel<<<grid, BLK, 0, stream>>>(x, scaler, out, nrows);
}

// Round 4
// 57.108 us; speedup vs baseline: 1.7992x; 1.1578x over previous
//
#include <hip/hip_runtime.h>

// QuantGelu: y = pre_x_int * sigmoid_int * (scaler/128)
//   pre_x_int = clip(round(x/scaler), -128, 127)  [per-channel scaler, D=4096]
//   sigmoid via integer shift-exp over {x_int, -row_max}
//
// Round-4 structure: sigmoid_int depends ONLY on (d = row_max - pre, x0),
// d in [0,255], x0 = floor(-1/(1.702 s)) a small negative int (~5-7 distinct
// values). Build per-block ei-table (block-invariant) and per-row sig-table
// in LDS; per-element phase 2 is one ds_read + 2 muls.

#define D 4096
#define BLK 512
#define CPT 8           // BLK*CPT == D
#define RPB 8
#define NW (BLK / 64)
#define NSLOT 16        // x0 slots covered by fast path
#define TENT (NSLOT * 256)
#define EPS 1e-4f
#define F2_31 2147483648.0f   // fl32(2^31 - 1)

// Exact floor(fl(xi/x0)) for integer-valued xi (|xi|<=384), integer x0 in
// [-64,-1]:
//  - divisible: t = (n(1+d1)+EPS)(1+d2), |n*d1| <= 384*6e-8 ~ 2.3e-5 < EPS,
//    EPS + err << 1 -> floor = n.
//  - else: |ratio - n| >= 1/|x0| >= 1/64 >> EPS + fma-err; and reference's
//    fl(xi/x0) can't cross an integer either (ulp(384) ~ 3e-5 << 1/64).
// ldexpf = v_ldexp_f32 (1 inst). Overflow -> inf, which only happens on the
// em path (q << 0) and is absorbed by min(esum, 2^31), matching np where
// exp2(15-q) = inf.
__device__ __forceinline__ float exp_fast(float xi, float nx0, float rx0) {
    const float q = floorf(fmaf(xi, rx0, EPS));
    const float r = fmaf(nx0, q, xi);      // xi - x0*q, exact (small ints)
    const float e = fmaf(r, 0.5f, nx0);    // r/2 - x0 in [0.5, 64], halves
    return floorf(ldexpf(e, 15 - (int)q)); // e > 0 -> max(.,0) redundant
}

// Fully-IEEE path, exact for any x0 (fallback only).
__device__ __forceinline__ float exp_slow(float xi, float x0) {
    xi = fmaxf(xi, 15.0f * x0);
    const float q = floorf(xi / x0);
    const float r = fmaf(-x0, q, xi);
    const float e = fmaf(r, 0.5f, -x0);
    return fmaxf(floorf(e * ldexpf(1.0f, 15 - (int)q)), 0.0f);
}

__global__ __launch_bounds__(BLK) void quantgelu_kernel(
    const float* __restrict__ x, const float* __restrict__ scaler,
    float* __restrict__ out, int nrows)
{
    const int tid = threadIdx.x;
    const int wid = tid >> 6;
    const int row0 = blockIdx.x * RPB;

    __shared__ __align__(16) float sred[2][NW];
    __shared__ __align__(16) float smax[NW];
    __shared__ float rx0t[NSLOT];
    __shared__ float eit[TENT];
    __shared__ float sigt[TENT];

    // ---- per-channel constants (hoisted across RPB rows) ----
    float s_[CPT], s128_[CPT], x0_[CPT];
    #pragma unroll
    for (int k = 0; k < CPT / 4; ++k) {
        const int col = k * (BLK * 4) + tid * 4;
        const float4 sv = *reinterpret_cast<const float4*>(scaler + col);
        const float ss[4] = {sv.x, sv.y, sv.z, sv.w};
        #pragma unroll
        for (int j = 0; j < 4; ++j) {
            const int i = k * 4 + j;
            s_[i]    = ss[j];
            s128_[i] = ss[j] * 0.0078125f;
            x0_[i]   = floorf(-1.0f / (ss[j] * 1.702f));   // IEEE div, 1x/8 rows
        }
    }

    // prefetch row 0 early
    long long base = (long long)row0 * D;
    float4 xv[CPT / 4];
    if (row0 < nrows) {
        #pragma unroll
        for (int k = 0; k < CPT / 4; ++k)
            xv[k] = *reinterpret_cast<const float4*>(x + base + k * (BLK * 4) + tid * 4);
    }

    // ---- block-wide x0 range (uniform: every block sees all D channels) ----
    float x0mn = x0_[0], x0mx = x0_[0];
    #pragma unroll
    for (int i = 1; i < CPT; ++i) {
        x0mn = fminf(x0mn, x0_[i]);
        x0mx = fmaxf(x0mx, x0_[i]);
    }
    #pragma unroll
    for (int off = 1; off < 64; off <<= 1) {
        x0mn = fminf(x0mn, __shfl_xor(x0mn, off));
        x0mx = fmaxf(x0mx, __shfl_xor(x0mx, off));
    }
    if ((tid & 63) == 0) { sred[0][wid] = x0mn; sred[1][wid] = x0mx; }
    __syncthreads();
    #pragma unroll
    for (int w = 0; w < NW; ++w) {
        x0mn = fminf(x0mn, sred[0][w]);
        x0mx = fmaxf(x0mx, sred[1][w]);
    }

    const int  nslots = (int)(x0mx - x0mn) + 1;
    const bool ok = (x0mn >= -64.0f) && (nslots <= NSLOT);   // block-uniform
    const int  nent = nslots << 8;

    int bo_[CPT];
    #pragma unroll
    for (int i = 0; i < CPT; ++i)
        bo_[i] = ((int)(x0_[i] - x0mn)) << 8;   // slot*256 (garbage if !ok, unused)

    // per-slot reciprocal (IEEE), once per block
    if (tid < NSLOT) rx0t[tid] = 1.0f / (x0mn + (float)tid);
    __syncthreads();

    // block-invariant ei table: ei(slot, d) = int_exp_shift(-d, x0_slot)
    if (ok) {
        for (int e = tid; e < nent; e += BLK) {
            const int   slot = e >> 8;
            const float x0v  = x0mn + (float)slot;
            float xi = -(float)(e & 255);
            xi = xi + floorf(xi * 0.5f) - floorf(xi * 0.0625f);
            xi = fmaxf(xi, 15.0f * x0v);
            eit[e] = exp_fast(xi, -x0v, rx0t[slot]);
        }
    }
    // (eit/rx0t writes ordered before first-row reads by syncA below)

    for (int r = 0; r < RPB; ++r) {
        const int row = row0 + r;
        if (row >= nrows) break;                // block-uniform

        // prefetch next row under this row's work
        float4 xn[CPT / 4];
        if (r + 1 < RPB && row + 1 < nrows) {
            #pragma unroll
            for (int k = 0; k < CPT / 4; ++k)
                xn[k] = *reinterpret_cast<const float4*>(x + base + D + k * (BLK * 4) + tid * 4);
        }

        // phase 1: quantize + row max
        float pre[CPT];
        float vmax = -INFINITY;
        const float* xf = reinterpret_cast<const float*>(xv);
        #pragma unroll
        for (int i = 0; i < CPT; ++i) {
            float p = rintf(xf[i] / s_[i]);     // IEEE div (exactness-critical)
            p = fminf(fmaxf(p, -128.0f), 127.0f);
            pre[i] = p;
            vmax = fmaxf(vmax, p);
        }
        #pragma unroll
        for (int off = 1; off < 64; off <<= 1)
            vmax = fmaxf(vmax, __shfl_xor(vmax, off));
        if ((tid & 63) == 0) smax[wid] = vmax;
        __syncthreads();                        // A (also orders eit/sigt reuse)
        {
            const float4 a = *reinterpret_cast<const float4*>(smax);
            const float4 b = *reinterpret_cast<const float4*>(smax + 4);
            vmax = fmaxf(fmaxf(fmaxf(a.x, a.y), fmaxf(a.z, a.w)),
                         fmaxf(fmaxf(b.x, b.y), fmaxf(b.z, b.w)));
        }

        const float xm  = -vmax;
        const float xmt = xm + floorf(xm * 0.5f) - floorf(xm * 0.0625f);

        // per-row sig table: sig(slot,d) = floor(ei*floor(2^31/min(ei+em,2^31))/2^24)
        if (ok) {
            for (int e = tid; e < nent; e += BLK) {
                const int   slot = e >> 8;
                const float x0v  = x0mn + (float)slot;
                const float em   = exp_fast(fmaxf(xmt, 15.0f * x0v), -x0v, rx0t[slot]);
                const float ei   = eit[e];
                const float esum   = fminf(ei + em, F2_31);
                const float factor = floorf(F2_31 / esum);        // IEEE div
                sigt[e] = floorf((ei * factor) * 0x1p-24f);
            }
        }
        __syncthreads();                        // B (sigt ready)

        float res[CPT];
        if (ok) {
            #pragma unroll
            for (int i = 0; i < CPT; ++i) {
                const int d   = (int)(vmax - pre[i]);   // exact, [0,255]
                const float sig = sigt[bo_[i] + d];     // LDS, off-VALU
                res[i] = (pre[i] * sig) * s128_[i];
            }
        } else {
            // rare block-uniform exact fallback (x0 out of table range)
            #pragma unroll
            for (int i = 0; i < CPT; ++i) {
                const float x0 = x0_[i];
                float xi = pre[i] - vmax;
                xi = xi + floorf(xi * 0.5f) - floorf(xi * 0.0625f);
                const float ei = exp_slow(xi, x0);
                const float em = exp_slow(xmt, x0);
                const float esum   = fminf(ei + em, F2_31);
                const float factor = floorf(F2_31 / esum);
                const float sig    = floorf((ei * factor) * 0x1p-24f);
                res[i] = (pre[i] * sig) * s128_[i];
            }
        }

        #pragma unroll
        for (int k = 0; k < CPT / 4; ++k) {
            float4 ov;
            ov.x = res[k * 4 + 0]; ov.y = res[k * 4 + 1];
            ov.z = res[k * 4 + 2]; ov.w = res[k * 4 + 3];
            *reinterpret_cast<float4*>(out + base + k * (BLK * 4) + tid * 4) = ov;
        }

        base += D;
        #pragma unroll
        for (int k = 0; k < CPT / 4; ++k) xv[k] = xn[k];
    }
}

extern "C" void kernel_launch(void* const* d_in, const int* in_sizes, int n_in,
                              void* d_out, int out_size, void* d_ws, size_t ws_size,
                              hipStream_t stream) {
    const float* x      = (const float*)d_in[0];
    const float* scaler = (const float*)d_in[1];
    float* out          = (float*)d_out;

    const int nrows = in_sizes[0] / D;                 // 8192
    const int grid  = (nrows + RPB - 1) / RPB;         // 1024
    quantgelu_kernel<<<grid, BLK, 0, stream>>>(x, scaler, out, nrows);
}

// Round 5
// 48.797 us; speedup vs baseline: 2.1057x; 1.1703x over previous
//
#include <hip/hip_runtime.h>

// QuantGelu: y = pre_x_int * sigmoid_int * (scaler/128)
//   pre_x_int = clip(round(x/scaler), -128, 127)  [per-channel scaler, D=4096]
//   sigmoid via integer shift-exp over {x_int, -row_max}
//
// Round-5: (1) Markstein correctly-rounded division for quantize (1/s hoisted
// per channel; 3 fma/elem replaces IEEE div); (2) em hoisted out of the sig
// build (per-lane slot em + __shfl); (3) non-temporal output stores (keep x
// L3-resident across replays). Table math identical to round 4 -> bit-same.

#define D 4096
#define BLK 512
#define CPT 8           // BLK*CPT == D
#define RPB 8
#define NW (BLK / 64)
#define NSLOT 16        // x0 slots covered by fast path
#define TENT (NSLOT * 256)
#define EPS 1e-4f
#define F2_31 2147483648.0f   // fl32(2^31 - 1)

typedef float f32x4 __attribute__((ext_vector_type(4)));

// Exact floor(fl(xi/x0)) for integer-valued xi, integer x0 in [-64,-1],
// ratio in [0,15] (clamped region):
//  - divisible: |fl(fma(xi,rx0,EPS)) - n - EPS| <= 15*2^-23 ~ 1.8e-6 << EPS,
//    EPS << 1 -> floor = n.
//  - else: |ratio - n| >= 1/|x0| >= 1/64 >> EPS + err; reference's fl(xi/x0)
//    (err <= 0.5 ulp(15) ~ 4.5e-7) can't cross an integer either.
// ldexpf = v_ldexp_f32. For the general (un-clamped em) path q<0 -> ldexp
// saturates to inf, matching np.exp2(15-q)=inf; absorbed by min(esum, 2^31).
__device__ __forceinline__ float exp_fast(float xi, float nx0, float rx0) {
    const float q = floorf(fmaf(xi, rx0, EPS));
    const float r = fmaf(nx0, q, xi);      // xi - x0*q, exact (small ints)
    const float e = fmaf(r, 0.5f, nx0);    // r/2 - x0, halves, exact
    return floorf(ldexpf(e, 15 - (int)q)); // e > 0 -> max(.,0) redundant
}

// Fully-IEEE path, exact for any x0 (fallback only).
__device__ __forceinline__ float exp_slow(float xi, float x0) {
    xi = fmaxf(xi, 15.0f * x0);
    const float q = floorf(xi / x0);
    const float r = fmaf(-x0, q, xi);
    const float e = fmaf(r, 0.5f, -x0);
    return fmaxf(floorf(e * ldexpf(1.0f, 15 - (int)q)), 0.0f);
}

__global__ __launch_bounds__(BLK) void quantgelu_kernel(
    const float* __restrict__ x, const float* __restrict__ scaler,
    float* __restrict__ out, int nrows)
{
    const int tid  = threadIdx.x;
    const int wid  = tid >> 6;
    const int lane = tid & 63;
    const int row0 = blockIdx.x * RPB;

    __shared__ __align__(16) float sred[2][NW];
    __shared__ __align__(16) float smax[NW];
    __shared__ float eit[TENT];
    __shared__ float sigt[TENT];

    // ---- per-channel constants (hoisted across RPB rows) ----
    float s_[CPT], rs_[CPT], s128_[CPT], x0_[CPT];
    #pragma unroll
    for (int k = 0; k < CPT / 4; ++k) {
        const int col = k * (BLK * 4) + tid * 4;
        const float4 sv = *reinterpret_cast<const float4*>(scaler + col);
        const float ss[4] = {sv.x, sv.y, sv.z, sv.w};
        #pragma unroll
        for (int j = 0; j < 4; ++j) {
            const int i = k * 4 + j;
            const float s = ss[j];
            s_[i]    = s;
            rs_[i]   = 1.0f / s;               // RN(1/s): Markstein seed, 1x/8 rows
            s128_[i] = s * 0.0078125f;
            x0_[i]   = floorf(-1.0f / (s * 1.702f));   // IEEE div, 1x/8 rows
        }
    }

    // prefetch row 0 early
    long long base = (long long)row0 * D;
    float4 xv[CPT / 4];
    if (row0 < nrows) {
        #pragma unroll
        for (int k = 0; k < CPT / 4; ++k)
            xv[k] = *reinterpret_cast<const float4*>(x + base + k * (BLK * 4) + tid * 4);
    }

    // ---- block-wide x0 range ----
    float x0mn = x0_[0], x0mx = x0_[0];
    #pragma unroll
    for (int i = 1; i < CPT; ++i) {
        x0mn = fminf(x0mn, x0_[i]);
        x0mx = fmaxf(x0mx, x0_[i]);
    }
    #pragma unroll
    for (int off = 1; off < 64; off <<= 1) {
        x0mn = fminf(x0mn, __shfl_xor(x0mn, off));
        x0mx = fmaxf(x0mx, __shfl_xor(x0mx, off));
    }
    if ((tid & 63) == 0) { sred[0][wid] = x0mn; sred[1][wid] = x0mx; }
    __syncthreads();
    #pragma unroll
    for (int w = 0; w < NW; ++w) {
        x0mn = fminf(x0mn, sred[0][w]);
        x0mx = fmaxf(x0mx, sred[1][w]);
    }

    const int  nslots = (int)(x0mx - x0mn) + 1;
    const bool ok = (x0mn >= -64.0f) && (nslots <= NSLOT);   // block-uniform
    const int  nent = nslots << 8;             // multiple of 256 -> wave-aligned

    int bo_[CPT];
    #pragma unroll
    for (int i = 0; i < CPT; ++i)
        bo_[i] = ((int)(x0_[i] - x0mn)) << 8;

    // lane-slot constants: lane l serves slot l (garbage for l >= nslots, unused)
    const float x0l  = x0mn + (float)lane;
    const float nx0l = -x0l;
    const float rx0l = 1.0f / x0l;              // IEEE div, 1x per block
    const float c15l = 15.0f * x0l;

    // block-invariant ei table: ei(slot, d) = int_exp_shift(-d, x0_slot)
    if (ok) {
        for (int e = tid; e < nent; e += BLK) {
            const int   slot = e >> 8;
            const float x0v  = x0mn + (float)slot;
            float xi = -(float)(e & 255);
            xi = xi + floorf(xi * 0.5f) - floorf(xi * 0.0625f);
            xi = fmaxf(xi, 15.0f * x0v);
            eit[e] = exp_fast(xi, -x0v, __shfl(rx0l, slot));
        }
    }
    // eit writes ordered before first build's reads by barrier A below.

    for (int r = 0; r < RPB; ++r) {
        const int row = row0 + r;
        if (row >= nrows) break;                // block-uniform

        // prefetch next row under this row's work
        float4 xn[CPT / 4];
        if (r + 1 < RPB && row + 1 < nrows) {
            #pragma unroll
            for (int k = 0; k < CPT / 4; ++k)
                xn[k] = *reinterpret_cast<const float4*>(x + base + D + k * (BLK * 4) + tid * 4);
        }

        // phase 1: quantize (Markstein correctly-rounded div) + row max
        float pre[CPT];
        float vmax = -INFINITY;
        const float* xf = reinterpret_cast<const float*>(xv);
        #pragma unroll
        for (int i = 0; i < CPT; ++i) {
            const float q0 = xf[i] * rs_[i];
            const float rr = fmaf(-s_[i], q0, xf[i]);
            const float qq = fmaf(rr, rs_[i], q0);   // = RN(x/s)
            float p = rintf(qq);
            p = fminf(fmaxf(p, -128.0f), 127.0f);
            pre[i] = p;
            vmax = fmaxf(vmax, p);
        }
        #pragma unroll
        for (int off = 1; off < 64; off <<= 1)
            vmax = fmaxf(vmax, __shfl_xor(vmax, off));
        if ((tid & 63) == 0) smax[wid] = vmax;
        __syncthreads();                        // A
        {
            const float4 a = *reinterpret_cast<const float4*>(smax);
            const float4 b = *reinterpret_cast<const float4*>(smax + 4);
            vmax = fmaxf(fmaxf(fmaxf(a.x, a.y), fmaxf(a.z, a.w)),
                         fmaxf(fmaxf(b.x, b.y), fmaxf(b.z, b.w)));
        }

        const float xm  = -vmax;
        const float xmt = xm + floorf(xm * 0.5f) - floorf(xm * 0.0625f);

        float res[CPT];
        if (ok) {
            // per-lane slot em, once per row (lanes >= nslots: unused garbage)
            const float em_l = exp_fast(fmaxf(xmt, c15l), nx0l, rx0l);

            // per-row sig table (nent wave-aligned -> whole waves at the shfl)
            for (int e = tid; e < nent; e += BLK) {
                const int   slot = e >> 8;
                const float em   = __shfl(em_l, slot);
                const float ei   = eit[e];
                const float esum   = fminf(ei + em, F2_31);
                const float factor = floorf(F2_31 / esum);    // IEEE div
                sigt[e] = floorf((ei * factor) * 0x1p-24f);
            }
            __syncthreads();                    // B (sigt ready)

            #pragma unroll
            for (int i = 0; i < CPT; ++i) {
                const int d = (int)(vmax - pre[i]);     // exact, [0,255]
                res[i] = (pre[i] * sigt[bo_[i] + d]) * s128_[i];
            }
        } else {
            // rare block-uniform exact fallback (x0 out of table range)
            #pragma unroll
            for (int i = 0; i < CPT; ++i) {
                const float x0 = x0_[i];
                float xi = pre[i] - vmax;
                xi = xi + floorf(xi * 0.5f) - floorf(xi * 0.0625f);
                const float ei = exp_slow(xi, x0);
                const float em = exp_slow(xmt, x0);
                const float esum   = fminf(ei + em, F2_31);
                const float factor = floorf(F2_31 / esum);
                const float sig    = floorf((ei * factor) * 0x1p-24f);
                res[i] = (pre[i] * sig) * s128_[i];
            }
        }

        // non-temporal stores: out is write-once; don't evict x from L2/L3
        #pragma unroll
        for (int k = 0; k < CPT / 4; ++k) {
            f32x4 ov;
            ov.x = res[k * 4 + 0]; ov.y = res[k * 4 + 1];
            ov.z = res[k * 4 + 2]; ov.w = res[k * 4 + 3];
            __builtin_nontemporal_store(
                ov, reinterpret_cast<f32x4*>(out + base + k * (BLK * 4) + tid * 4));
        }

        base += D;
        #pragma unroll
        for (int k = 0; k < CPT / 4; ++k) xv[k] = xn[k];
    }
}

extern "C" void kernel_launch(void* const* d_in, const int* in_sizes, int n_in,
                              void* d_out, int out_size, void* d_ws, size_t ws_size,
                              hipStream_t stream) {
    const float* x      = (const float*)d_in[0];
    const float* scaler = (const float*)d_in[1];
    float* out          = (float*)d_out;

    const int nrows = in_sizes[0] / D;                 // 8192
    const int grid  = (nrows + RPB - 1) / RPB;         // 1024
    quantgelu_kernel<<<grid, BLK, 0, stream>>>(x, scaler, out, nrows);
}